// Round 3
// baseline (1261.696 us; speedup 1.0000x reference)
//
#include <hip/hip_runtime.h>
#include <cstdint>
#include <cstddef>

#define NNODES 100000
#define NEDGES 1600000
#define DIM 128
#define NREL 8
#define NSEG (NNODES * NREL)                       // 800,000 segments
#define SCAN_BLK 2048
#define NSCAN ((NSEG + SCAN_BLK - 1) / SCAN_BLK)   // 391 scan blocks
#define NKT 36                                     // 1152 / 32 K-steps
#define A16ROW 1160                                // f16 LDS row stride (ushorts)
#define CVT4 (NNODES * DIM / 4)                    // 3,200,000 float4 groups
#define CVT_BLKS ((CVT4 + 255) / 256)              // 12,500
#define PACK_UNITS (NKT * 8 * 2)                   // 576 64-lane pack units
#define PACK_BLKS ((PACK_UNITS + 3) / 4)           // 144

typedef float f32x4 __attribute__((ext_vector_type(4)));
typedef short short4v __attribute__((ext_vector_type(4)));
typedef short short8 __attribute__((ext_vector_type(8)));
typedef _Float16 half4v __attribute__((ext_vector_type(4)));
typedef _Float16 half8 __attribute__((ext_vector_type(8)));

__device__ inline float h2f(unsigned short u) {
    return (float)__builtin_bit_cast(_Float16, u);
}
__device__ inline unsigned short f2h(float f) {
    return __builtin_bit_cast(unsigned short, (_Float16)f);
}

// --------------------------------------- count + cvt + weight-pack (fused) --
__global__ __launch_bounds__(256) void count_cvt(const int* __restrict__ dst,
                                                 const int* __restrict__ et,
                                                 int* __restrict__ cnt,
                                                 const float* __restrict__ x,
                                                 unsigned short* __restrict__ xh,
                                                 const float* __restrict__ Wrel1,
                                                 const float* __restrict__ Wroot1,
                                                 const float* __restrict__ Wrel2,
                                                 const float* __restrict__ Wroot2,
                                                 unsigned short* __restrict__ Wp1,
                                                 unsigned short* __restrict__ Wp2) {
    int b = blockIdx.x;
    if (b < CVT_BLKS) {
        int gid = b * 256 + threadIdx.x;
        if (gid < NEDGES) atomicAdd(&cnt[dst[gid] * NREL + et[gid]], 1);
        if (gid < CVT4) {
            float4 v = *(const float4*)(x + (size_t)gid * 4);
            ushort4 o = make_ushort4(f2h(v.x), f2h(v.y), f2h(v.z), f2h(v.w));
            *(ushort4*)(xh + (size_t)gid * 4) = o;
        }
        return;
    }
    // weight packing: 4 units per block, 64 lanes per unit
    int unit = (b - CVT_BLKS) * 4 + (threadIdx.x >> 6);
    if (unit >= PACK_UNITS) return;
    int lane = threadIdx.x & 63;
    int bb = unit;
    const float* Wrel = Wrel1;
    const float* Wroot = Wroot1;
    unsigned short* Wp = Wp1;
    if (bb >= NKT * 8) {
        bb -= NKT * 8;
        Wrel = Wrel2; Wroot = Wroot2; Wp = Wp2;
    }
    const int kt = bb >> 3, ht = bb & 7;
    const int col = ht * 16 + (lane & 15);
    const int kbase = kt * 32 + (lane >> 4) * 8;
    unsigned short vals[8];
#pragma unroll
    for (int j = 0; j < 8; ++j) {
        int k = kbase + j;
        float f = (k < 1024) ? Wrel[(size_t)k * 128 + col]
                             : Wroot[(size_t)(k - 1024) * 128 + col];
        vals[j] = f2h(f);
    }
    unsigned short* dstp = Wp + ((size_t)bb * 64 + lane) * 8;
#pragma unroll
    for (int j = 0; j < 8; ++j) dstp[j] = vals[j];
}

// ------------------------------------------------- scan pass1 (+inv fuse) ---
__global__ __launch_bounds__(256) void scan_pass1(const int* __restrict__ cnt,
                                                  int* __restrict__ bsum,
                                                  float* __restrict__ inv) {
    int base = blockIdx.x * SCAN_BLK + threadIdx.x * 8;
    int s = 0;
#pragma unroll
    for (int j = 0; j < 8; ++j) {
        int i = base + j;
        if (i < NSEG) {
            int c = cnt[i];
            s += c;
            inv[i] = 1.0f / (float)(c > 1 ? c : 1);
        }
    }
    __shared__ int ws[4];
    for (int d = 1; d < 64; d <<= 1) s += __shfl_xor(s, d);
    int lane = threadIdx.x & 63, w = threadIdx.x >> 6;
    if (lane == 0) ws[w] = s;
    __syncthreads();
    if (threadIdx.x == 0) bsum[blockIdx.x] = ws[0] + ws[1] + ws[2] + ws[3];
}

__global__ __launch_bounds__(64) void scan_pass2(int* __restrict__ bsum) {
    int lane = threadIdx.x;
    int vals[7];
    int s = 0;
#pragma unroll
    for (int j = 0; j < 7; ++j) {
        int i = lane * 7 + j;
        vals[j] = (i < NSCAN) ? bsum[i] : 0;
        s += vals[j];
    }
    int incl = s;
    for (int d = 1; d < 64; d <<= 1) {
        int u = __shfl_up(incl, d);
        if (lane >= d) incl += u;
    }
    int base = incl - s;
#pragma unroll
    for (int j = 0; j < 7; ++j) {
        int i = lane * 7 + j;
        if (i < NSCAN) bsum[i] = base;
        base += vals[j];
    }
}

__global__ __launch_bounds__(256) void scan_pass3(const int* __restrict__ cnt,
                                                  const int* __restrict__ bsum,
                                                  int* __restrict__ segend) {
    int tid = threadIdx.x;
    int base = blockIdx.x * SCAN_BLK + tid * 8;
    int v[8];
    int s = 0;
#pragma unroll
    for (int j = 0; j < 8; ++j) {
        int i = base + j;
        v[j] = (i < NSEG) ? cnt[i] : 0;
        s += v[j];
    }
    int lane = tid & 63, w = tid >> 6;
    int incl = s;
    for (int d = 1; d < 64; d <<= 1) {
        int u = __shfl_up(incl, d);
        if (lane >= d) incl += u;
    }
    __shared__ int wtot[4];
    if (lane == 63) wtot[w] = incl;
    __syncthreads();
    int wbase = 0;
#pragma unroll
    for (int k = 0; k < 4; ++k)
        if (k < w) wbase += wtot[k];
    int tbase = bsum[blockIdx.x] + wbase + (incl - s);
#pragma unroll
    for (int j = 0; j < 8; ++j) {
        int i = base + j;
        if (i < NSEG) segend[i] = tbase;   // becomes segment END after bucketing
        tbase += v[j];
    }
}

// --------------------------------------------------------------- bucket ----
// einfo[p] = src | (rel << 20)   (src < 2^20)
__global__ __launch_bounds__(256) void bucket_kernel(const int* __restrict__ src,
                                                     const int* __restrict__ dst,
                                                     const int* __restrict__ et,
                                                     int* __restrict__ segend,
                                                     int* __restrict__ einfo) {
    int e = blockIdx.x * 256 + threadIdx.x;
    if (e >= NEDGES) return;
    int seg = dst[e] * NREL + et[e];
    int p = atomicAdd(&segend[seg], 1);
    einfo[p] = src[e] | ((seg & 7) << 20);
}

// ---------------------------------------------------------- fused layer ----
// 512 threads, 16 nodes/block, 32 lanes/node (8 B/lane per edge row).
// Phase 1: explicit 2-buffer chunk pipeline, live set ~70 VGPR (fits the
//          launch_bounds(512,6) cap of ~85 -> no scratch, unlike round 2).
//          sched_barrier(0) pins load batches above compute.
// Phase 2: 8 waves x 1 h-tile, 36 K-steps mfma_f32_16x16x32_f16.
#define LOADQ(Q, BASE)                                                         \
    _Pragma("unroll")                                                          \
    for (int u = 0; u < 8; ++u) {                                              \
        int p = (BASE) + u;                                                    \
        Q[u] = einfo[p < last ? p : last];                                     \
    }

#define LOADV(V, Q)                                                            \
    _Pragma("unroll")                                                          \
    for (int u = 0; u < 8; ++u)                                                \
        V[u] = *(const short4v*)(feat + (size_t)(Q[u] & 0xFFFFF) * DIM + l32 * 4);

#define FLUSH4 {                                                               \
    float sc = __shfl(invv, cur, 32);                                          \
    short4v o;                                                                 \
    _Pragma("unroll")                                                          \
    for (int j = 0; j < 4; ++j) o[j] = (short)f2h(accv[j] * sc);               \
    *(short4v*)(Arow + cur * DIM + l32 * 4) = o;                               \
    accv = (f32x4){0.f, 0.f, 0.f, 0.f};                                        \
}

#define COMP_FULL(Q, V)                                                        \
    _Pragma("unroll")                                                          \
    for (int u = 0; u < 8; ++u) {                                              \
        int s = ((unsigned)Q[u]) >> 20;                                        \
        if (s != cur) { FLUSH4 cur = s; }                                      \
        accv += __builtin_convertvector(__builtin_bit_cast(half4v, V[u]), f32x4); \
    }

#define COMP_TAIL(Q, V, EB)                                                    \
    _Pragma("unroll")                                                          \
    for (int u = 0; u < 8; ++u) {                                              \
        if ((EB) + u < ecnt) {                                                 \
            int s = ((unsigned)Q[u]) >> 20;                                    \
            if (s != cur) { FLUSH4 cur = s; }                                  \
            accv += __builtin_convertvector(__builtin_bit_cast(half4v, V[u]), f32x4); \
        }                                                                      \
    }

__global__ __launch_bounds__(512, 6) void fused_layer(
    const unsigned short* __restrict__ feat,   // f16 [N][128]
    const int* __restrict__ segend,
    const int* __restrict__ einfo,
    const unsigned short* __restrict__ Wp,     // packed f16 B-frags
    const float* __restrict__ bias,
    const float* __restrict__ inv,
    unsigned short* __restrict__ out,          // f16 [N][128] (ignored in head mode)
    const float* __restrict__ outw,            // non-null => head mode
    const float* __restrict__ outb,
    float* __restrict__ head_out) {
    __shared__ __align__(16) unsigned short A16[16 * A16ROW + 8];
    const int tid = threadIdx.x;
    const int blk = blockIdx.x;
    const int g = tid >> 5, l32 = tid & 31;    // 16 groups of 32 lanes

    // --- segment metadata (longest dependency chain: issue first) ---
    const int n = blk * 16 + g;
    const int segbase = n * NREL;
    const int se = segend[segbase + (l32 & 7)];
    const float invv = inv[segbase + (l32 & 7)];
    int prev = 0;
    if (l32 == 0) prev = (segbase == 0) ? 0 : segend[segbase - 1];

    // root row load (independent; overlaps segend)
    const short4v rootv =
        *(const short4v*)(feat + ((size_t)blk * 16 + g) * DIM + l32 * 4);

    prev = __shfl(prev, 0, 32);
    const int beg = prev;
    const int end = __shfl(se, 7, 32);
    const int ecnt = end - beg;

    unsigned short* Arow = &A16[g * A16ROW];

    if (ecnt > 0) {
        const int last = end - 1;
        int qA[8], qB[8];
        short4v vX[8], vY[8];
        LOADQ(qA, beg)
        LOADQ(qB, beg + 8)
        LOADV(vX, qA)
        __builtin_amdgcn_sched_barrier(0);

        // stage root row + zero empty relation rows while gathers fly
        *(short4v*)(Arow + 1024 + l32 * 4) = rootv;
        {
            int b = prev;
#pragma unroll
            for (int r = 0; r < 8; ++r) {
                int er = __shfl(se, r, 32);
                if (er == b) {
                    short4v z = {0, 0, 0, 0};
                    *(short4v*)(Arow + r * DIM + l32 * 4) = z;
                }
                b = er;
            }
        }

        f32x4 accv = {0.f, 0.f, 0.f, 0.f};
        int cur = ((unsigned)qA[0]) >> 20;
        const int nch = (ecnt + 7) >> 3;
        int c = 0;
        for (;;) {
            // ---- half A: compute chunk c from qA/vX ----
            if (c + 1 < nch) { LOADV(vY, qB) }
            __builtin_amdgcn_sched_barrier(0);
            if (c + 1 == nch) { COMP_TAIL(qA, vX, c * 8) break; }
            COMP_FULL(qA, vX)
            if (c + 2 < nch) { LOADQ(qA, beg + (c + 2) * 8) }
            __builtin_amdgcn_sched_barrier(0);
            ++c;
            // ---- half B: compute chunk c from qB/vY ----
            if (c + 1 < nch) { LOADV(vX, qA) }
            __builtin_amdgcn_sched_barrier(0);
            if (c + 1 == nch) { COMP_TAIL(qB, vY, c * 8) break; }
            COMP_FULL(qB, vY)
            if (c + 2 < nch) { LOADQ(qB, beg + (c + 2) * 8) }
            __builtin_amdgcn_sched_barrier(0);
            ++c;
        }
        FLUSH4   // final flush
    } else {
        // no in-edges: stage root row, zero all relation rows
        *(short4v*)(Arow + 1024 + l32 * 4) = rootv;
        short4v z = {0, 0, 0, 0};
#pragma unroll
        for (int r = 0; r < 8; ++r)
            *(short4v*)(Arow + r * DIM + l32 * 4) = z;
    }

    // ---- phase 2: MFMA, 8 waves x 1 h-tile ----
    const int lane = tid & 63;
    const int w = tid >> 6;                 // wave id == h-tile id (0..7)
    const int m = lane & 15, kq = lane >> 4;
    const unsigned short* arow = &A16[m * A16ROW + kq * 8];
    const unsigned short* bb0 = Wp + ((size_t)w * 64 + lane) * 8;

    short8 pb0 = *(const short8*)bb0;       // kt=0 frag flies during barrier
    __syncthreads();

    f32x4 acc0 = {0.f, 0.f, 0.f, 0.f};
    {
        short8 a = *(const short8*)arow;
        acc0 = __builtin_amdgcn_mfma_f32_16x16x32_f16(
            __builtin_bit_cast(half8, a), __builtin_bit_cast(half8, pb0), acc0, 0, 0, 0);
    }
#pragma unroll 5
    for (int kt = 1; kt < NKT; ++kt) {
        short8 a = *(const short8*)(arow + kt * 32);
        short8 b0 = *(const short8*)(bb0 + (size_t)kt * 4096);
        acc0 = __builtin_amdgcn_mfma_f32_16x16x32_f16(
            __builtin_bit_cast(half8, a), __builtin_bit_cast(half8, b0), acc0, 0, 0, 0);
    }

    // ---- epilogue (C/D: col=lane&15, row=kq*4+r) ----
    const int col = lane & 15;
    const int h0 = 16 * w + col;
    const float bv0 = bias[h0];

    if (!head_out) {
        // layer 1: bias + relu + f16 store
#pragma unroll
        for (int r = 0; r < 4; ++r) {
            const size_t nrow = ((size_t)blk * 16 + kq * 4 + r) * DIM;
            out[nrow + h0] = f2h(fmaxf(acc0[r] + bv0, 0.f));
        }
    } else {
        // layer 2 + head: relu'd h dot out_w, reduce, sigmoid (no h2 roundtrip)
        const float w0 = outw[h0];
        float part[4];
#pragma unroll
        for (int r = 0; r < 4; ++r) {
            part[r] = fmaxf(acc0[r] + bv0, 0.f) * w0;
#pragma unroll
            for (int d = 1; d < 16; d <<= 1)
                part[r] += __shfl_xor(part[r], d, 16);   // sum over 16 col-lanes
        }
        __syncthreads();                 // all A16 reads done; reuse LDS
        float* hp = (float*)A16;         // hp[node_local][wave]
        if (col == 0) {
#pragma unroll
            for (int r = 0; r < 4; ++r) hp[(kq * 4 + r) * 8 + w] = part[r];
        }
        __syncthreads();
        if (tid < 16) {
            float vsum = outb[0];
#pragma unroll
            for (int k = 0; k < 8; ++k) vsum += hp[tid * 8 + k];
            head_out[blk * 16 + tid] = 1.0f / (1.0f + __expf(-vsum));
        }
    }
}

// ---------------------------------------------------------------- launch ----
extern "C" void kernel_launch(void* const* d_in, const int* in_sizes, int n_in,
                              void* d_out, int out_size, void* d_ws, size_t ws_size,
                              hipStream_t stream) {
    const float* x      = (const float*)d_in[0];
    const int*   ei     = (const int*)d_in[1];
    const int*   et     = (const int*)d_in[2];
    const float* Wrel1  = (const float*)d_in[3];
    const float* Wroot1 = (const float*)d_in[4];
    const float* b1     = (const float*)d_in[5];
    const float* Wrel2  = (const float*)d_in[6];
    const float* Wroot2 = (const float*)d_in[7];
    const float* b2     = (const float*)d_in[8];
    const float* outw   = (const float*)d_in[9];
    const float* outb   = (const float*)d_in[10];
    const int* src = ei;
    const int* dst = ei + NEDGES;

    // workspace layout (~68 MB, 16B-aligned chunks)
    char* ws = (char*)d_ws;
    int*            cnt    = (int*)(ws + 0);                     //  3,200,000
    int*            bsum   = (int*)(ws + 3200000);               //      4,096
    int*            segend = (int*)(ws + 3204096);               //  3,200,000
    int*            einfo  = (int*)(ws + 6404096);               //  6,400,000
    unsigned short* xh     = (unsigned short*)(ws + 12804096);   // 25,600,000
    unsigned short* h1     = (unsigned short*)(ws + 38404096);   // 25,600,000
    unsigned short* Wp1    = (unsigned short*)(ws + 64004096);   //    294,912
    unsigned short* Wp2    = (unsigned short*)(ws + 64299008);   //    294,912
    float*          inv    = (float*)(ws + 64593920);            //  3,200,000
    // end: 67,793,920 B

    hipMemsetAsync(cnt, 0, (size_t)NSEG * 4, stream);
    count_cvt<<<CVT_BLKS + PACK_BLKS, 256, 0, stream>>>(dst, et, cnt, x, xh,
                                                        Wrel1, Wroot1, Wrel2, Wroot2,
                                                        Wp1, Wp2);
    scan_pass1<<<NSCAN, 256, 0, stream>>>(cnt, bsum, inv);
    scan_pass2<<<1, 64, 0, stream>>>(bsum);
    scan_pass3<<<NSCAN, 256, 0, stream>>>(cnt, bsum, segend);
    bucket_kernel<<<(NEDGES + 255) / 256, 256, 0, stream>>>(src, dst, et, segend, einfo);

    fused_layer<<<NNODES / 16, 512, 0, stream>>>(xh, segend, einfo, Wp1, b1, inv,
                                                 h1, nullptr, nullptr, nullptr);
    fused_layer<<<NNODES / 16, 512, 0, stream>>>(h1, segend, einfo, Wp2, b2, inv,
                                                 nullptr, outw, outb, (float*)d_out);
}

// Round 4
// 506.701 us; speedup vs baseline: 2.4900x; 2.4900x over previous
//
#include <hip/hip_runtime.h>
#include <cstdint>
#include <cstddef>

#define NNODES 100000
#define NEDGES 1600000
#define DIM 128
#define NREL 8
#define NSEG (NNODES * NREL)                       // 800,000 segments
#define SCAN_BLK 2048
#define NSCAN ((NSEG + SCAN_BLK - 1) / SCAN_BLK)   // 391 scan blocks
#define NKT 36                                     // 1152 / 32 K-steps
#define A16ROW 1160                                // f16 LDS row stride (ushorts)
#define CVT4 (NNODES * DIM / 4)                    // 3,200,000 float4 groups
#define CVT_BLKS ((CVT4 + 255) / 256)              // 12,500
#define PACK_UNITS (NKT * 8 * 2)                   // 576 64-lane pack units
#define PACK_BLKS ((PACK_UNITS + 3) / 4)           // 144

typedef float f32x4 __attribute__((ext_vector_type(4)));
typedef short short4v __attribute__((ext_vector_type(4)));
typedef short short8 __attribute__((ext_vector_type(8)));
typedef _Float16 half4v __attribute__((ext_vector_type(4)));
typedef _Float16 half8 __attribute__((ext_vector_type(8)));

__device__ inline float h2f(unsigned short u) {
    return (float)__builtin_bit_cast(_Float16, u);
}
__device__ inline unsigned short f2h(float f) {
    return __builtin_bit_cast(unsigned short, (_Float16)f);
}

// --------------------------------------- count + cvt + weight-pack (fused) --
__global__ __launch_bounds__(256) void count_cvt(const int* __restrict__ dst,
                                                 const int* __restrict__ et,
                                                 int* __restrict__ cnt,
                                                 const float* __restrict__ x,
                                                 unsigned short* __restrict__ xh,
                                                 const float* __restrict__ Wrel1,
                                                 const float* __restrict__ Wroot1,
                                                 const float* __restrict__ Wrel2,
                                                 const float* __restrict__ Wroot2,
                                                 unsigned short* __restrict__ Wp1,
                                                 unsigned short* __restrict__ Wp2) {
    int b = blockIdx.x;
    if (b < CVT_BLKS) {
        int gid = b * 256 + threadIdx.x;
        if (gid < NEDGES) atomicAdd(&cnt[dst[gid] * NREL + et[gid]], 1);
        if (gid < CVT4) {
            float4 v = *(const float4*)(x + (size_t)gid * 4);
            ushort4 o = make_ushort4(f2h(v.x), f2h(v.y), f2h(v.z), f2h(v.w));
            *(ushort4*)(xh + (size_t)gid * 4) = o;
        }
        return;
    }
    // weight packing: 4 units per block, 64 lanes per unit
    int unit = (b - CVT_BLKS) * 4 + (threadIdx.x >> 6);
    if (unit >= PACK_UNITS) return;
    int lane = threadIdx.x & 63;
    int bb = unit;
    const float* Wrel = Wrel1;
    const float* Wroot = Wroot1;
    unsigned short* Wp = Wp1;
    if (bb >= NKT * 8) {
        bb -= NKT * 8;
        Wrel = Wrel2; Wroot = Wroot2; Wp = Wp2;
    }
    const int kt = bb >> 3, ht = bb & 7;
    const int col = ht * 16 + (lane & 15);
    const int kbase = kt * 32 + (lane >> 4) * 8;
    unsigned short vals[8];
#pragma unroll
    for (int j = 0; j < 8; ++j) {
        int k = kbase + j;
        float f = (k < 1024) ? Wrel[(size_t)k * 128 + col]
                             : Wroot[(size_t)(k - 1024) * 128 + col];
        vals[j] = f2h(f);
    }
    unsigned short* dstp = Wp + ((size_t)bb * 64 + lane) * 8;
#pragma unroll
    for (int j = 0; j < 8; ++j) dstp[j] = vals[j];
}

// ------------------------------------------------- scan pass1 (+inv fuse) ---
__global__ __launch_bounds__(256) void scan_pass1(const int* __restrict__ cnt,
                                                  int* __restrict__ bsum,
                                                  float* __restrict__ inv) {
    int base = blockIdx.x * SCAN_BLK + threadIdx.x * 8;
    int s = 0;
#pragma unroll
    for (int j = 0; j < 8; ++j) {
        int i = base + j;
        if (i < NSEG) {
            int c = cnt[i];
            s += c;
            inv[i] = 1.0f / (float)(c > 1 ? c : 1);
        }
    }
    __shared__ int ws[4];
    for (int d = 1; d < 64; d <<= 1) s += __shfl_xor(s, d);
    int lane = threadIdx.x & 63, w = threadIdx.x >> 6;
    if (lane == 0) ws[w] = s;
    __syncthreads();
    if (threadIdx.x == 0) bsum[blockIdx.x] = ws[0] + ws[1] + ws[2] + ws[3];
}

__global__ __launch_bounds__(64) void scan_pass2(int* __restrict__ bsum) {
    int lane = threadIdx.x;
    int vals[7];
    int s = 0;
#pragma unroll
    for (int j = 0; j < 7; ++j) {
        int i = lane * 7 + j;
        vals[j] = (i < NSCAN) ? bsum[i] : 0;
        s += vals[j];
    }
    int incl = s;
    for (int d = 1; d < 64; d <<= 1) {
        int u = __shfl_up(incl, d);
        if (lane >= d) incl += u;
    }
    int base = incl - s;
#pragma unroll
    for (int j = 0; j < 7; ++j) {
        int i = lane * 7 + j;
        if (i < NSCAN) bsum[i] = base;
        base += vals[j];
    }
}

__global__ __launch_bounds__(256) void scan_pass3(const int* __restrict__ cnt,
                                                  const int* __restrict__ bsum,
                                                  int* __restrict__ segend) {
    int tid = threadIdx.x;
    int base = blockIdx.x * SCAN_BLK + tid * 8;
    int v[8];
    int s = 0;
#pragma unroll
    for (int j = 0; j < 8; ++j) {
        int i = base + j;
        v[j] = (i < NSEG) ? cnt[i] : 0;
        s += v[j];
    }
    int lane = tid & 63, w = tid >> 6;
    int incl = s;
    for (int d = 1; d < 64; d <<= 1) {
        int u = __shfl_up(incl, d);
        if (lane >= d) incl += u;
    }
    __shared__ int wtot[4];
    if (lane == 63) wtot[w] = incl;
    __syncthreads();
    int wbase = 0;
#pragma unroll
    for (int k = 0; k < 4; ++k)
        if (k < w) wbase += wtot[k];
    int tbase = bsum[blockIdx.x] + wbase + (incl - s);
#pragma unroll
    for (int j = 0; j < 8; ++j) {
        int i = base + j;
        if (i < NSEG) segend[i] = tbase;   // becomes segment END after bucketing
        tbase += v[j];
    }
}

// --------------------------------------------------------------- bucket ----
// einfo[p] = src | (rel << 20)   (src < 2^20)
__global__ __launch_bounds__(256) void bucket_kernel(const int* __restrict__ src,
                                                     const int* __restrict__ dst,
                                                     const int* __restrict__ et,
                                                     int* __restrict__ segend,
                                                     int* __restrict__ einfo) {
    int e = blockIdx.x * 256 + threadIdx.x;
    if (e >= NEDGES) return;
    int seg = dst[e] * NREL + et[e];
    int p = atomicAdd(&segend[seg], 1);
    einfo[p] = src[e] | ((seg & 7) << 20);
}

// ---------------------------------------------------------- fused layer ----
// 512 threads (8 waves), 16 nodes/block, 32 lanes/node, 8 B/lane per edge row.
// Occupancy math: LDS 37.4 KB -> 4 blocks/CU; 4 x 8 waves = 32 waves/CU = 100%
// IF VGPR <= 64 (launch_bounds(512,8)). Live set ~50 VGPR with the 8B/lane
// buffers, so the cap holds without spilling (round 2/3's sched_barrier(0)
// fences -- the proven spill trigger -- are gone; round-0 loop structure).
// Phase 2: 8 waves x 1 h-tile, 36 K-steps mfma_f32_16x16x32_f16.
#define FLUSH4 {                                                               \
    float sc = __shfl(invv, cur, 32);                                          \
    short4v o;                                                                 \
    _Pragma("unroll")                                                          \
    for (int j = 0; j < 4; ++j) o[j] = (short)f2h(accv[j] * sc);               \
    *(short4v*)(Arow + cur * DIM + l32 * 4) = o;                               \
    accv = (f32x4){0.f, 0.f, 0.f, 0.f};                                        \
}

__global__ __launch_bounds__(512, 8) void fused_layer(
    const unsigned short* __restrict__ feat,   // f16 [N][128]
    const int* __restrict__ segend,
    const int* __restrict__ einfo,
    const unsigned short* __restrict__ Wp,     // packed f16 B-frags
    const float* __restrict__ bias,
    const float* __restrict__ inv,
    unsigned short* __restrict__ out,          // f16 [N][128] (ignored in head mode)
    const float* __restrict__ outw,            // non-null => head mode
    const float* __restrict__ outb,
    float* __restrict__ head_out) {
    __shared__ __align__(16) unsigned short A16[16 * A16ROW + 8];
    const int tid = threadIdx.x;
    const int blk = blockIdx.x;
    const int g = tid >> 5, l32 = tid & 31;    // 16 groups of 32 lanes

    // --- segment metadata (longest dependency chain: issue first) ---
    const int n = blk * 16 + g;
    const int segbase = n * NREL;
    const int se = segend[segbase + (l32 & 7)];
    const float invv = inv[segbase + (l32 & 7)];
    int prev = 0;
    if (l32 == 0) prev = (segbase == 0) ? 0 : segend[segbase - 1];

    // root row load (independent; overlaps segend)
    const short4v rootv =
        *(const short4v*)(feat + ((size_t)blk * 16 + g) * DIM + l32 * 4);

    prev = __shfl(prev, 0, 32);
    const int beg = prev;
    const int end = __shfl(se, 7, 32);
    const int ecnt = end - beg;

    unsigned short* Arow = &A16[g * A16ROW];

    // stage root row; zero empty relation rows
    *(short4v*)(Arow + 1024 + l32 * 4) = rootv;
    {
        int b = prev;
#pragma unroll
        for (int r = 0; r < 8; ++r) {
            int er = __shfl(se, r, 32);
            if (er == b) {
                short4v z = {0, 0, 0, 0};
                *(short4v*)(Arow + r * DIM + l32 * 4) = z;
            }
            b = er;
        }
    }

    if (ecnt > 0) {
        const int last = end - 1;
        int q[8], qn[8];
        short4v v[8];
#pragma unroll
        for (int u = 0; u < 8; ++u) {
            int p = beg + u;
            q[u] = einfo[p < last ? p : last];
        }
#pragma unroll
        for (int u = 0; u < 8; ++u)
            v[u] = *(const short4v*)(feat + (size_t)(q[u] & 0xFFFFF) * DIM + l32 * 4);

        f32x4 accv = {0.f, 0.f, 0.f, 0.f};
        int cur = ((unsigned)q[0]) >> 20;

        for (int e = beg; e < end; e += 8) {
            // prefetch next einfo chunk (broadcast loads, L1-resident)
#pragma unroll
            for (int u = 0; u < 8; ++u) {
                int p = e + 8 + u;
                qn[u] = einfo[p < last ? p : last];
            }
            // compute current chunk
#pragma unroll
            for (int u = 0; u < 8; ++u) {
                if (e + u < end) {
                    const int s = ((unsigned)q[u]) >> 20;
                    if (s != cur) { FLUSH4 cur = s; }
                    accv += __builtin_convertvector(
                        __builtin_bit_cast(half4v, v[u]), f32x4);
                }
            }
            // issue next chunk's feature gathers (addresses already known)
#pragma unroll
            for (int u = 0; u < 8; ++u) {
                v[u] = *(const short4v*)(feat + (size_t)(qn[u] & 0xFFFFF) * DIM + l32 * 4);
                q[u] = qn[u];
            }
        }
        FLUSH4   // final flush (scale + store)
    }
    __syncthreads();

    // ---- phase 2: MFMA, 8 waves x 1 h-tile ----
    const int lane = tid & 63;
    const int w = tid >> 6;                 // wave id == h-tile id (0..7)
    const int m = lane & 15, kq = lane >> 4;
    const unsigned short* arow = &A16[m * A16ROW + kq * 8];
    const unsigned short* bb0 = Wp + ((size_t)w * 64 + lane) * 8;

    f32x4 acc0 = {0.f, 0.f, 0.f, 0.f};
#pragma unroll 6
    for (int kt = 0; kt < NKT; ++kt) {
        short8 a = *(const short8*)(arow + kt * 32);
        short8 b0 = *(const short8*)(bb0 + (size_t)kt * 4096);
        acc0 = __builtin_amdgcn_mfma_f32_16x16x32_f16(
            __builtin_bit_cast(half8, a), __builtin_bit_cast(half8, b0), acc0, 0, 0, 0);
    }

    // ---- epilogue (C/D: col=lane&15, row=kq*4+r) ----
    const int col = lane & 15;
    const int h0 = 16 * w + col;
    const float bv0 = bias[h0];

    if (!head_out) {
        // layer 1: bias + relu + f16 store
#pragma unroll
        for (int r = 0; r < 4; ++r) {
            const size_t nrow = ((size_t)blk * 16 + kq * 4 + r) * DIM;
            out[nrow + h0] = f2h(fmaxf(acc0[r] + bv0, 0.f));
        }
    } else {
        // layer 2 + head: relu'd h dot out_w, reduce, sigmoid (no h2 roundtrip)
        const float w0 = outw[h0];
        float part[4];
#pragma unroll
        for (int r = 0; r < 4; ++r) {
            part[r] = fmaxf(acc0[r] + bv0, 0.f) * w0;
#pragma unroll
            for (int d = 1; d < 16; d <<= 1)
                part[r] += __shfl_xor(part[r], d, 16);   // sum over 16 col-lanes
        }
        __syncthreads();                 // all A16 reads done; reuse LDS
        float* hp = (float*)A16;         // hp[node_local][wave]
        if (col == 0) {
#pragma unroll
            for (int r = 0; r < 4; ++r) hp[(kq * 4 + r) * 8 + w] = part[r];
        }
        __syncthreads();
        if (tid < 16) {
            float vsum = outb[0];
#pragma unroll
            for (int k = 0; k < 8; ++k) vsum += hp[tid * 8 + k];
            head_out[blk * 16 + tid] = 1.0f / (1.0f + __expf(-vsum));
        }
    }
}

// ---------------------------------------------------------------- launch ----
extern "C" void kernel_launch(void* const* d_in, const int* in_sizes, int n_in,
                              void* d_out, int out_size, void* d_ws, size_t ws_size,
                              hipStream_t stream) {
    const float* x      = (const float*)d_in[0];
    const int*   ei     = (const int*)d_in[1];
    const int*   et     = (const int*)d_in[2];
    const float* Wrel1  = (const float*)d_in[3];
    const float* Wroot1 = (const float*)d_in[4];
    const float* b1     = (const float*)d_in[5];
    const float* Wrel2  = (const float*)d_in[6];
    const float* Wroot2 = (const float*)d_in[7];
    const float* b2     = (const float*)d_in[8];
    const float* outw   = (const float*)d_in[9];
    const float* outb   = (const float*)d_in[10];
    const int* src = ei;
    const int* dst = ei + NEDGES;

    // workspace layout (~68 MB, 16B-aligned chunks)
    char* ws = (char*)d_ws;
    int*            cnt    = (int*)(ws + 0);                     //  3,200,000
    int*            bsum   = (int*)(ws + 3200000);               //      4,096
    int*            segend = (int*)(ws + 3204096);               //  3,200,000
    int*            einfo  = (int*)(ws + 6404096);               //  6,400,000
    unsigned short* xh     = (unsigned short*)(ws + 12804096);   // 25,600,000
    unsigned short* h1     = (unsigned short*)(ws + 38404096);   // 25,600,000
    unsigned short* Wp1    = (unsigned short*)(ws + 64004096);   //    294,912
    unsigned short* Wp2    = (unsigned short*)(ws + 64299008);   //    294,912
    float*          inv    = (float*)(ws + 64593920);            //  3,200,000
    // end: 67,793,920 B

    hipMemsetAsync(cnt, 0, (size_t)NSEG * 4, stream);
    count_cvt<<<CVT_BLKS + PACK_BLKS, 256, 0, stream>>>(dst, et, cnt, x, xh,
                                                        Wrel1, Wroot1, Wrel2, Wroot2,
                                                        Wp1, Wp2);
    scan_pass1<<<NSCAN, 256, 0, stream>>>(cnt, bsum, inv);
    scan_pass2<<<1, 64, 0, stream>>>(bsum);
    scan_pass3<<<NSCAN, 256, 0, stream>>>(cnt, bsum, segend);
    bucket_kernel<<<(NEDGES + 255) / 256, 256, 0, stream>>>(src, dst, et, segend, einfo);

    fused_layer<<<NNODES / 16, 512, 0, stream>>>(xh, segend, einfo, Wp1, b1, inv,
                                                 h1, nullptr, nullptr, nullptr);
    fused_layer<<<NNODES / 16, 512, 0, stream>>>(h1, segend, einfo, Wp2, b2, inv,
                                                 nullptr, outw, outb, (float*)d_out);
}